// Round 1
// baseline (50.164 us; speedup 1.0000x reference)
//
#include <hip/hip_runtime.h>
#include <math.h>

#define N_USERS 200000
#define N_ITEMS 200000
#define HOPS 4
#define DIM 64
#define BATCH 2048
#define N_NEGS 64
#define KK 2
#define ROW 256          // HOPS*DIM
#define DECAY 0.0001f

// One block per batch element. 256 threads = 4 waves.
// Each wave handles one candidate at a time: lane l covers row elements [4l, 4l+3]
// (hop = l>>4, c4 = (l&15)*4). Wave loads a full 1KB item row as float4/lane.
__global__ __launch_bounds__(256, 4) void mixgcf_main(
    const float* __restrict__ user_emb,
    const float* __restrict__ item_emb,
    const float* __restrict__ seed_embed,
    const int*   __restrict__ user,
    const int*   __restrict__ pos_item,
    const int*   __restrict__ neg_item,
    float*       __restrict__ ws)
{
    const int b    = blockIdx.x;
    const int tid  = threadIdx.x;
    const int w    = tid >> 6;     // wave id 0..3
    const int lane = tid & 63;

    __shared__ float s_lds[ROW];          // user row,  layout [h*64 + c]
    __shared__ float p_lds[ROW];          // pos-item row
    __shared__ int   nidx[KK * N_NEGS];   // 128 candidate indices
    __shared__ float selv[KK][ROW];       // selected mixed rows
    __shared__ float scw[4][HOPS];        // per-wave best score per hop

    const int   uidx = user[b];
    const int   pidx = pos_item[b];
    const float seed = seed_embed[b];

    // Cooperative staging: 64 thr -> s_e (float4), 64 thr -> p_e, 128 thr -> neg indices
    if (tid < 64) {
        ((float4*)s_lds)[tid] = *(const float4*)(user_emb + (size_t)uidx * ROW + tid * 4);
    } else if (tid < 128) {
        ((float4*)p_lds)[tid - 64] = *(const float4*)(item_emb + (size_t)pidx * ROW + (tid - 64) * 4);
    } else {
        nidx[tid - 128] = neg_item[(size_t)b * (KK * N_NEGS) + (tid - 128)];
    }
    __syncthreads();

    // Per-lane fragments (same for all 4 waves: each wave scans whole candidates)
    const float4 s4 = *(const float4*)(s_lds + lane * 4);
    const float4 p4 = *(const float4*)(p_lds + lane * 4);
    const float  omse = 1.0f - seed;
    const float4 sp = make_float4(seed * p4.x, seed * p4.y, seed * p4.z, seed * p4.w);
    const int h = lane >> 4;   // hop this lane's 16-group owns

    for (int k = 0; k < KK; ++k) {
        float  best = -INFINITY;
        float4 bv   = make_float4(0.f, 0.f, 0.f, 0.f);

        #pragma unroll 4
        for (int i = 0; i < 16; ++i) {
            const int n  = (i << 2) + w;              // candidate index within this k-slice
            const int it = nidx[k * N_NEGS + n];      // wave-uniform (broadcast read)
            const float4 ne = *(const float4*)(item_emb + (size_t)it * ROW + lane * 4);
            float4 ne_;
            ne_.x = fmaf(omse, ne.x, sp.x);
            ne_.y = fmaf(omse, ne.y, sp.y);
            ne_.z = fmaf(omse, ne.z, sp.z);
            ne_.w = fmaf(omse, ne.w, sp.w);
            float sc = ne_.x * s4.x;
            sc = fmaf(ne_.y, s4.y, sc);
            sc = fmaf(ne_.z, s4.z, sc);
            sc = fmaf(ne_.w, s4.w, sc);
            // reduce over the 16-lane hop group (xor masks stay in-group)
            sc += __shfl_xor(sc, 1);
            sc += __shfl_xor(sc, 2);
            sc += __shfl_xor(sc, 4);
            sc += __shfl_xor(sc, 8);
            // group-uniform compare; keep winning mixed value in registers.
            // Exact ties only arise from duplicate item ids -> identical values,
            // so tie-break order cannot change the output.
            if (sc > best) { best = sc; bv = ne_; }
        }

        // cross-wave argmax per hop
        if ((lane & 15) == 0) scw[w][h] = best;
        __syncthreads();
        float m0 = scw[0][h], m1 = scw[1][h], m2 = scw[2][h], m3 = scw[3][h];
        int winner = 0; float mb = m0;
        if (m1 > mb) { mb = m1; winner = 1; }
        if (m2 > mb) { mb = m2; winner = 2; }
        if (m3 > mb) { mb = m3; winner = 3; }
        if (w == winner) {
            *(float4*)(&selv[k][lane * 4]) = bv;
        }
        __syncthreads();   // selv complete; scw reusable next k
    }

    // Epilogue: wave 0, lane c = channel
    if (w == 0) {
        const int c = lane;
        const float ue = 0.25f * (s_lds[c] + s_lds[64 + c] + s_lds[128 + c] + s_lds[192 + c]);
        const float pe = 0.25f * (p_lds[c] + p_lds[64 + c] + p_lds[128 + c] + p_lds[192 + c]);
        const float n0 = 0.25f * (selv[0][c] + selv[0][64 + c] + selv[0][128 + c] + selv[0][192 + c]);
        const float n1 = 0.25f * (selv[1][c] + selv[1][64 + c] + selv[1][128 + c] + selv[1][192 + c]);
        float ps  = ue * pe;
        float ns0 = ue * n0;
        float ns1 = ue * n1;
        float rg  = ue * ue + pe * pe + n0 * n0 + n1 * n1;
        #pragma unroll
        for (int m = 1; m < 64; m <<= 1) {
            ps  += __shfl_xor(ps,  m);
            ns0 += __shfl_xor(ns0, m);
            ns1 += __shfl_xor(ns1, m);
            rg  += __shfl_xor(rg,  m);
        }
        if (lane == 0) {
            const float mf = log1pf(expf(ns0 - ps) + expf(ns1 - ps));
            ws[b]         = mf;
            ws[BATCH + b] = rg;
        }
    }
}

// Deterministic final reduction: one block, fixed tree.
__global__ __launch_bounds__(256) void mixgcf_reduce(const float* __restrict__ ws,
                                                     float* __restrict__ out)
{
    __shared__ float smf[256];
    __shared__ float srg[256];
    const int t = threadIdx.x;
    float mf = 0.f, rg = 0.f;
    for (int i = t; i < BATCH; i += 256) {
        mf += ws[i];
        rg += ws[BATCH + i];
    }
    smf[t] = mf; srg[t] = rg;
    __syncthreads();
    for (int s = 128; s > 0; s >>= 1) {
        if (t < s) { smf[t] += smf[t + s]; srg[t] += srg[t + s]; }
        __syncthreads();
    }
    if (t == 0) {
        const float mf_loss  = smf[0] / (float)BATCH;
        const float emb_loss = DECAY * (srg[0] * 0.5f) / (float)BATCH;
        out[0] = mf_loss + emb_loss;
        out[1] = mf_loss;
        out[2] = emb_loss;
    }
}

extern "C" void kernel_launch(void* const* d_in, const int* in_sizes, int n_in,
                              void* d_out, int out_size, void* d_ws, size_t ws_size,
                              hipStream_t stream)
{
    const float* user_emb  = (const float*)d_in[0];
    const float* item_emb  = (const float*)d_in[1];
    const float* seed      = (const float*)d_in[2];
    const int*   user      = (const int*)d_in[3];
    const int*   pos_item  = (const int*)d_in[4];
    const int*   neg_item  = (const int*)d_in[5];
    float* ws  = (float*)d_ws;
    float* out = (float*)d_out;

    mixgcf_main<<<BATCH, 256, 0, stream>>>(user_emb, item_emb, seed,
                                           user, pos_item, neg_item, ws);
    mixgcf_reduce<<<1, 256, 0, stream>>>(ws, out);
}